// Round 12
// baseline (237.026 us; speedup 1.0000x reference)
//
#include <hip/hip_runtime.h>
#include <math.h>

#define S_TOK 128
#define PS_O 257    // float stride for mirror staging rows
#define TILES_PER_BLOCK 3
#define NBLOCKS 768        // 2304 tiles / 3

// Abuf: 256 rows x 128 bytes (64 bf16) with XOR swizzle -> 32 KiB exact.
#define SWZ(row, byteoff) ((((row) * 128) + (byteoff)) ^ (((row) & 7) << 4))

// ws float layout
#define OFF_A1 0      // [64][4] f32 folded layer-1 weights
#define OFF_C1 256    // [64] f32
#define OFF_C2 320
#define OFF_C3 384
#define OFF_BF 448    // ushort region: A2bf[64*64], then A3bf[64*64]

using bf16x8 = __attribute__((ext_vector_type(8))) __bf16;
using f32x4  = __attribute__((ext_vector_type(4))) float;

__device__ __forceinline__ unsigned short f2bf(float v) {
    unsigned u = __builtin_bit_cast(unsigned, v);
    u += 0x7fffu + ((u >> 16) & 1u);      // round-to-nearest-even
    return (unsigned short)(u >> 16);
}

// tanh-form gelu via HW transcendentals (~9 VALU ops vs ~105 for libm erff).
__device__ __forceinline__ float gelu_fast(float v) {
    float v2 = v * v;
    float z  = v * fmaf(0.044715f, v2, 1.0f);
    float u  = z * 2.3022082f;            // 2 * 0.7978845608 * log2(e)
    float e;
    asm("v_exp_f32 %0, %1" : "=v"(e) : "v"(u));
    float d = e + 1.0f;
    float r;
    asm("v_rcp_f32 %0, %1" : "=v"(r) : "v"(d));
    return fmaf(-v, r, v);                // v*(1-r); e=inf -> v, e=0 -> 0
}

// Workgroup barrier that waits only for LDS ops (lgkmcnt), NOT vmcnt:
// keeps global stores in flight across barriers -- this is what lets tile s's
// stores drain underneath tile s+1's compute (the pipelining mechanism).
__device__ __forceinline__ void lds_barrier() {
    asm volatile("s_waitcnt lgkmcnt(0)" ::: "memory");
    __builtin_amdgcn_s_barrier();
}

__global__ void fold_weights_kernel(
    const float* __restrict__ bn0g, const float* __restrict__ bn0b,
    const float* __restrict__ bn0m, const float* __restrict__ bn0v,
    const float* __restrict__ W1,  const float* __restrict__ b1,
    const float* __restrict__ bn1g, const float* __restrict__ bn1b,
    const float* __restrict__ bn1m, const float* __restrict__ bn1v,
    const float* __restrict__ W2,  const float* __restrict__ b2,
    const float* __restrict__ bn2g, const float* __restrict__ bn2b,
    const float* __restrict__ bn2m, const float* __restrict__ bn2v,
    const float* __restrict__ W3,  const float* __restrict__ b3,
    const float* __restrict__ bn3g, const float* __restrict__ bn3b,
    const float* __restrict__ bn3m, const float* __restrict__ bn3v,
    float* __restrict__ ws)
{
    int o = threadIdx.x;
    if (o >= 64) return;
    float s0[4], t0[4];
    #pragma unroll
    for (int c = 0; c < 4; ++c) {
        float s = bn0g[c] / sqrtf(bn0v[c] + 1e-5f);
        s0[c] = s;
        t0[c] = bn0b[c] - bn0m[c] * s;
    }
    float s1 = bn1g[o] / sqrtf(bn1v[o] + 1e-5f);
    float acc = b1[o] - bn1m[o];
    #pragma unroll
    for (int c = 0; c < 4; ++c) {
        float w = W1[o*4 + c];
        ws[OFF_A1 + o*4 + c] = s1 * w * s0[c];
        acc += w * t0[c];
    }
    ws[OFF_C1 + o] = s1 * acc + bn1b[o];

    unsigned short* wsbf = (unsigned short*)(ws + OFF_BF);
    unsigned short* A2bf = wsbf;
    unsigned short* A3bf = wsbf + 4096;

    float s2 = bn2g[o] / sqrtf(bn2v[o] + 1e-5f);
    for (int c = 0; c < 64; ++c) A2bf[o*64 + c] = f2bf(W2[o*64 + c] * s2);
    ws[OFF_C2 + o] = (b2[o] - bn2m[o]) * s2 + bn2b[o];

    float s3 = bn3g[o] / sqrtf(bn3v[o] + 1e-5f);
    for (int c = 0; c < 64; ++c) A3bf[o*64 + c] = f2bf(W3[o*64 + c] * s3);
    ws[OFF_C3 + o] = (b3[o] - bn3m[o]) * s3 + bn3b[o];
}

// Block = 3 tril tiles processed sequentially (software pipeline): the global
// stores of tile s (fire-and-forget, no vmcnt waits) drain during tile s+1's
// feature/MLP compute. This breaks the phase-alignment serialization where
// all resident blocks hit the store phase simultaneously (r3..r10 all fit a
// serial-sum model: VALU 17 + LDS 24 + stores 38 ~= 76us measured).
// launch_bounds (256,4): (256,5) spills (116us, r4+r11). Do not raise.
__global__ __launch_bounds__(256, 4) void pair_mlp_mfma(
    const float* __restrict__ x, const float* __restrict__ ws,
    float* __restrict__ y)
{
    __shared__ __align__(16) unsigned char Abuf[32768];

    const int tid  = threadIdx.x;
    const int lane = tid & 63;
    const int wv   = tid >> 6;      // wave 0..3
    const int lcol = lane & 15;     // MFMA row/col-in-frag
    const int lgrp = lane >> 4;     // MFMA k-group 0..3
    const int li = tid >> 4;
    const int lj = tid & 15;

    const float* A1 = ws + OFF_A1;
    const float* C1 = ws + OFF_C1;
    const unsigned short* A2bf = (const unsigned short*)(ws + OFF_BF);
    const unsigned short* A3bf = A2bf + 4096;
    const float* C2 = ws + OFF_C2;
    const float* C3 = ws + OFF_C3;

    #pragma unroll 1
    for (int s = 0; s < TILES_PER_BLOCK; ++s) {
        const int t_lin = (int)blockIdx.x + s * NBLOCKS;   // 0..2303
        const int t = t_lin % 36;
        const int b = t_lin / 36;
        int I = (int)((sqrtf(8.0f * (float)t + 1.0f) - 1.0f) * 0.5f);
        while ((I + 1) * (I + 2) / 2 <= t) ++I;
        while (I * (I + 1) / 2 > t) --I;
        const int J = t - I * (I + 1) / 2;

        const int i = I * 16 + li;
        const int j = J * 16 + lj;

        // ---- pairwise LV features (fp32, jnp semantics) ----
        const float* xb = x + (size_t)b * 4 * S_TOK;
        const float pxi = xb[0*S_TOK + i], pyi = xb[1*S_TOK + i];
        const float pzi = xb[2*S_TOK + i], ei  = xb[3*S_TOK + i];
        const float pxj = xb[0*S_TOK + j], pyj = xb[1*S_TOK + j];
        const float pzj = xb[2*S_TOK + j], ej  = xb[3*S_TOK + j];

        const float pti = sqrtf(pxi*pxi + pyi*pyi);
        const float ptj = sqrtf(pxj*pxj + pyj*pyj);
        const float rapi = 0.5f * log1pf(2.0f * pzi / fmaxf(ei - pzi, 1e-20f));
        const float rapj = 0.5f * log1pf(2.0f * pzj / fmaxf(ej - pzj, 1e-20f));
        const float phii = atan2f(pyi, pxi);
        const float phij = atan2f(pyj, pxj);

        const float PI_F    = 3.14159265358979323846f;
        const float TWOPI_F = 6.28318530717958647692f;
        float dx   = phii - phij + PI_F;
        float dphi = dx - TWOPI_F * floorf(dx * (1.0f / TWOPI_F)) - PI_F;
        float drap = rapi - rapj;
        float delta = sqrtf(drap*drap + dphi*dphi);
        float lndelta = logf(fmaxf(delta, 1e-8f));
        float ptmin = fminf(pti, ptj);
        float f0 = logf(fmaxf(ptmin * delta, 1e-8f));
        float f1 = logf(fmaxf(ptmin / fmaxf(pti + ptj, 1e-8f), 1e-8f));
        float f2 = lndelta;
        float sx = pxi + pxj, sy = pyi + pyj, sz = pzi + pzj, se = ei + ej;
        float f3 = logf(fmaxf(se*se - sx*sx - sy*sy - sz*sz, 1e-8f));

        // Abuf reuse across iterations: prior tile's last Abuf readers
        // (layer-3 frags / Obuf mirror reads) must finish first.
        lds_barrier();

        // ---- layer 1 (fp32) + gelu -> bf16 -> LDS (swizzled rows) ----
        #pragma unroll
        for (int oc = 0; oc < 8; ++oc) {
            unsigned pk[4];
            #pragma unroll
            for (int q = 0; q < 4; ++q) {
                const int o0 = oc*8 + 2*q;
                float z0 = C1[o0]   + A1[o0*4+0]*f0 + A1[o0*4+1]*f1
                                    + A1[o0*4+2]*f2 + A1[o0*4+3]*f3;
                float z1 = C1[o0+1] + A1[(o0+1)*4+0]*f0 + A1[(o0+1)*4+1]*f1
                                    + A1[(o0+1)*4+2]*f2 + A1[(o0+1)*4+3]*f3;
                z0 = gelu_fast(z0);
                z1 = gelu_fast(z1);
                pk[q] = (unsigned)f2bf(z0) | ((unsigned)f2bf(z1) << 16);
            }
            uint4 v; v.x = pk[0]; v.y = pk[1]; v.z = pk[2]; v.w = pk[3];
            *reinterpret_cast<uint4*>(Abuf + SWZ(tid, oc*16)) = v;
        }
        lds_barrier();

        // ---- layer 2 ----
        f32x4 acc2[4][4];
        #pragma unroll
        for (int mt = 0; mt < 4; ++mt)
            #pragma unroll
            for (int nt = 0; nt < 4; ++nt)
                acc2[mt][nt] = f32x4{0.f, 0.f, 0.f, 0.f};
        {
            bf16x8 wf[4][2];
            #pragma unroll
            for (int nt = 0; nt < 4; ++nt)
                #pragma unroll
                for (int kt = 0; kt < 2; ++kt)
                    wf[nt][kt] = *reinterpret_cast<const bf16x8*>(
                        A2bf + (nt*16 + lcol)*64 + kt*32 + lgrp*8);
            #pragma unroll
            for (int kt = 0; kt < 2; ++kt) {
                bf16x8 af[4];
                #pragma unroll
                for (int mt = 0; mt < 4; ++mt)
                    af[mt] = *reinterpret_cast<const bf16x8*>(
                        Abuf + SWZ(wv*64 + mt*16 + lcol, kt*64 + lgrp*16));
                #pragma unroll
                for (int mt = 0; mt < 4; ++mt)
                    #pragma unroll
                    for (int nt = 0; nt < 4; ++nt)
                        acc2[mt][nt] = __builtin_amdgcn_mfma_f32_16x16x32_bf16(
                            af[mt], wf[nt][kt], acc2[mt][nt], 0, 0, 0);
            }
        }
        lds_barrier();   // all layer-2 reads of Abuf done

        // bias + gelu -> bf16 a2 back into Abuf
        #pragma unroll
        for (int nt = 0; nt < 4; ++nt) {
            const float bias = C2[nt*16 + lcol];
            #pragma unroll
            for (int mt = 0; mt < 4; ++mt)
                #pragma unroll
                for (int r = 0; r < 4; ++r) {
                    float z = acc2[mt][nt][r] + bias;
                    *reinterpret_cast<unsigned short*>(
                        Abuf + SWZ(wv*64 + mt*16 + 4*lgrp + r, (nt*16 + lcol)*2))
                        = f2bf(gelu_fast(z));
                }
        }
        lds_barrier();

        // ---- layer 3 (no gelu) ----
        f32x4 acc3[4][4];
        #pragma unroll
        for (int mt = 0; mt < 4; ++mt)
            #pragma unroll
            for (int nt = 0; nt < 4; ++nt)
                acc3[mt][nt] = f32x4{0.f, 0.f, 0.f, 0.f};
        {
            bf16x8 wf[4][2];
            #pragma unroll
            for (int nt = 0; nt < 4; ++nt)
                #pragma unroll
                for (int kt = 0; kt < 2; ++kt)
                    wf[nt][kt] = *reinterpret_cast<const bf16x8*>(
                        A3bf + (nt*16 + lcol)*64 + kt*32 + lgrp*8);
            #pragma unroll
            for (int kt = 0; kt < 2; ++kt) {
                bf16x8 af[4];
                #pragma unroll
                for (int mt = 0; mt < 4; ++mt)
                    af[mt] = *reinterpret_cast<const bf16x8*>(
                        Abuf + SWZ(wv*64 + mt*16 + lcol, kt*64 + lgrp*16));
                #pragma unroll
                for (int mt = 0; mt < 4; ++mt)
                    #pragma unroll
                    for (int nt = 0; nt < 4; ++nt)
                        acc3[mt][nt] = __builtin_amdgcn_mfma_f32_16x16x32_bf16(
                            af[mt], wf[nt][kt], acc3[mt][nt], 0, 0, 0);
            }
        }

        // ---- output ----
        const size_t ybase = (size_t)b * 64 * (S_TOK * S_TOK);
        const bool diag = (I == J);

        if (diag) {
            #pragma unroll
            for (int nt = 0; nt < 4; ++nt) {
                const float bias3 = C3[nt*16 + lcol];
                #pragma unroll
                for (int mt = 0; mt < 4; ++mt) {
                    f32x4 v = acc3[mt][nt] + bias3;
                    *reinterpret_cast<f32x4*>(
                        &y[ybase + (size_t)(nt*16 + lcol)*(S_TOK*S_TOK)
                                 + (16*I + 4*wv + mt)*S_TOK + 16*J + 4*lgrp]) = v;
                }
            }
        } else {
            float* Obuf = reinterpret_cast<float*>(Abuf);   // [16][PS_O]
            const int jd = tid & 15;
            const int g2 = (tid >> 4) & 3;
            lds_barrier();   // all layer-3 Abuf reads done before Obuf clobbers

            for (int nt = 0; nt < 4; ++nt) {
                const float bias3 = C3[nt*16 + lcol];
                #pragma unroll
                for (int mt = 0; mt < 4; ++mt) {
                    f32x4 v = acc3[mt][nt] + bias3;
                    *reinterpret_cast<f32x4*>(
                        &y[ybase + (size_t)(nt*16 + lcol)*(S_TOK*S_TOK)
                                 + (16*I + 4*wv + mt)*S_TOK + 16*J + 4*lgrp]) = v;
                    const int il = 4*wv + mt;
                    #pragma unroll
                    for (int r = 0; r < 4; ++r) {
                        const int jl = 4*lgrp + r;
                        Obuf[lcol*PS_O + il*16 + ((jl + il) & 15)] = v[r];
                    }
                }
                lds_barrier();   // staging visible; stores stay in flight
                #pragma unroll
                for (int k = 0; k < 16; ++k) {
                    const int ol = 4*(k & 3) + wv;
                    const int o  = nt*16 + ol;
                    const int il = 4*(k >> 2) + g2;
                    const float vmir = Obuf[ol*PS_O + jd*16 + ((il + jd) & 15)];
                    y[ybase + (size_t)o*(S_TOK*S_TOK)
                            + (16*J + il)*S_TOK + 16*I + jd] = vmir;
                }
                lds_barrier();   // Obuf reads done before next staging
            }
        }
    }
}

extern "C" void kernel_launch(void* const* d_in, const int* in_sizes, int n_in,
                              void* d_out, int out_size, void* d_ws, size_t ws_size,
                              hipStream_t stream) {
    const float* x    = (const float*)d_in[0];
    const float* bn0g = (const float*)d_in[1];
    const float* bn0b = (const float*)d_in[2];
    const float* bn0m = (const float*)d_in[3];
    const float* bn0v = (const float*)d_in[4];
    const float* W1   = (const float*)d_in[5];
    const float* b1   = (const float*)d_in[6];
    const float* bn1g = (const float*)d_in[7];
    const float* bn1b = (const float*)d_in[8];
    const float* bn1m = (const float*)d_in[9];
    const float* bn1v = (const float*)d_in[10];
    const float* W2   = (const float*)d_in[11];
    const float* b2   = (const float*)d_in[12];
    const float* bn2g = (const float*)d_in[13];
    const float* bn2b = (const float*)d_in[14];
    const float* bn2m = (const float*)d_in[15];
    const float* bn2v = (const float*)d_in[16];
    const float* W3   = (const float*)d_in[17];
    const float* b3   = (const float*)d_in[18];
    const float* bn3g = (const float*)d_in[19];
    const float* bn3b = (const float*)d_in[20];
    const float* bn3m = (const float*)d_in[21];
    const float* bn3v = (const float*)d_in[22];

    float* ws = (float*)d_ws;
    float* y  = (float*)d_out;

    fold_weights_kernel<<<1, 64, 0, stream>>>(
        bn0g, bn0b, bn0m, bn0v, W1, b1, bn1g, bn1b, bn1m, bn1v,
        W2, b2, bn2g, bn2b, bn2m, bn2v, W3, b3, bn3g, bn3b, bn3m, bn3v, ws);

    pair_mlp_mfma<<<NBLOCKS, 256, 0, stream>>>(x, ws, y);
}

// Round 13
// 83.499 us; speedup vs baseline: 2.8387x; 2.8387x over previous
//
#include <hip/hip_runtime.h>
#include <math.h>

#define S_TOK 128

// Abuf: 256 rows x 128 bytes (64 bf16), XOR row-hash swizzle -> 32 KiB exact.
// Hash (row ^ row>>4)&7 keeps layer-1 b128 writes and direct frag reads in
// the same (conflict-free) class as the old row&7 hash, AND makes the
// TRANSPOSED pass-2 frag reads (rows = lcol*16 + const) 2-way instead of
// 16-way (row>>4 = lcol enters the bank bits).
#define SWZ(row, byteoff) ((((row) * 128) + (byteoff)) ^ ((((row) ^ ((row) >> 4)) & 7) << 4))

// ws float layout
#define OFF_A1 0      // [64][4] f32 folded layer-1 weights
#define OFF_C1 256    // [64] f32
#define OFF_C2 320
#define OFF_C3 384
#define OFF_BF 448    // ushort region: A2bf[64*64], then A3bf[64*64]

using bf16x8 = __attribute__((ext_vector_type(8))) __bf16;
using f32x4  = __attribute__((ext_vector_type(4))) float;

__device__ __forceinline__ unsigned short f2bf(float v) {
    unsigned u = __builtin_bit_cast(unsigned, v);
    u += 0x7fffu + ((u >> 16) & 1u);      // round-to-nearest-even
    return (unsigned short)(u >> 16);
}

// tanh-form gelu via HW transcendentals (~9 VALU ops vs ~105 for libm erff).
__device__ __forceinline__ float gelu_fast(float v) {
    float v2 = v * v;
    float z  = v * fmaf(0.044715f, v2, 1.0f);
    float u  = z * 2.3022082f;            // 2 * 0.7978845608 * log2(e)
    float e;
    asm("v_exp_f32 %0, %1" : "=v"(e) : "v"(u));
    float d = e + 1.0f;
    float r;
    asm("v_rcp_f32 %0, %1" : "=v"(r) : "v"(d));
    return fmaf(-v, r, v);                // v*(1-r); e=inf -> v, e=0 -> 0
}

__global__ void fold_weights_kernel(
    const float* __restrict__ bn0g, const float* __restrict__ bn0b,
    const float* __restrict__ bn0m, const float* __restrict__ bn0v,
    const float* __restrict__ W1,  const float* __restrict__ b1,
    const float* __restrict__ bn1g, const float* __restrict__ bn1b,
    const float* __restrict__ bn1m, const float* __restrict__ bn1v,
    const float* __restrict__ W2,  const float* __restrict__ b2,
    const float* __restrict__ bn2g, const float* __restrict__ bn2b,
    const float* __restrict__ bn2m, const float* __restrict__ bn2v,
    const float* __restrict__ W3,  const float* __restrict__ b3,
    const float* __restrict__ bn3g, const float* __restrict__ bn3b,
    const float* __restrict__ bn3m, const float* __restrict__ bn3v,
    float* __restrict__ ws)
{
    int o = threadIdx.x;
    if (o >= 64) return;
    float s0[4], t0[4];
    #pragma unroll
    for (int c = 0; c < 4; ++c) {
        float s = bn0g[c] / sqrtf(bn0v[c] + 1e-5f);
        s0[c] = s;
        t0[c] = bn0b[c] - bn0m[c] * s;
    }
    float s1 = bn1g[o] / sqrtf(bn1v[o] + 1e-5f);
    float acc = b1[o] - bn1m[o];
    #pragma unroll
    for (int c = 0; c < 4; ++c) {
        float w = W1[o*4 + c];
        ws[OFF_A1 + o*4 + c] = s1 * w * s0[c];
        acc += w * t0[c];
    }
    ws[OFF_C1 + o] = s1 * acc + bn1b[o];

    unsigned short* wsbf = (unsigned short*)(ws + OFF_BF);
    unsigned short* A2bf = wsbf;
    unsigned short* A3bf = wsbf + 4096;

    float s2 = bn2g[o] / sqrtf(bn2v[o] + 1e-5f);
    for (int c = 0; c < 64; ++c) A2bf[o*64 + c] = f2bf(W2[o*64 + c] * s2);
    ws[OFF_C2 + o] = (b2[o] - bn2m[o]) * s2 + bn2b[o];

    float s3 = bn3g[o] / sqrtf(bn3v[o] + 1e-5f);
    for (int c = 0; c < 64; ++c) A3bf[o*64 + c] = f2bf(W3[o*64 + c] * s3);
    ws[OFF_C3 + o] = (b3[o] - bn3m[o]) * s3 + bn3b[o];
}

// Block = (tril tile t, batch b). 256 threads = 4 waves.
// h(i,j)=h(j,i). Direct region: layer-3 MFMA pass 1, register-direct dwordx4
// stores. Mirror region: layer-3 MFMA pass 2 with TRANSPOSED-pair A-frags
// (row' = lcol*16 + wv*4 + mt reads a2[swap(pair)]), register-direct dwordx4
// stores -- no LDS staging, no store-phase barriers, kernel ends in pure
// fire-and-forget stores. Diagonal tiles skip pass 2.
// launch_bounds (256,4): (256,5) spills (116us, r4+r11). Do not raise.
__global__ __launch_bounds__(256, 4) void pair_mlp_mfma(
    const float* __restrict__ x, const float* __restrict__ ws,
    float* __restrict__ y)
{
    __shared__ __align__(16) unsigned char Abuf[32768];

    const int t = blockIdx.x;
    const int b = blockIdx.y;
    int I = (int)((sqrtf(8.0f * (float)t + 1.0f) - 1.0f) * 0.5f);
    while ((I + 1) * (I + 2) / 2 <= t) ++I;
    while (I * (I + 1) / 2 > t) --I;
    const int J = t - I * (I + 1) / 2;

    const int tid  = threadIdx.x;
    const int lane = tid & 63;
    const int wv   = tid >> 6;      // wave 0..3
    const int lcol = lane & 15;     // MFMA row/col-in-frag
    const int lgrp = lane >> 4;     // MFMA k-group 0..3

    // ---- pairwise LV features (fp32, jnp semantics) ----
    const int li = tid >> 4;
    const int lj = tid & 15;
    const int i = I * 16 + li;
    const int j = J * 16 + lj;

    const float* xb = x + (size_t)b * 4 * S_TOK;
    const float pxi = xb[0*S_TOK + i], pyi = xb[1*S_TOK + i];
    const float pzi = xb[2*S_TOK + i], ei  = xb[3*S_TOK + i];
    const float pxj = xb[0*S_TOK + j], pyj = xb[1*S_TOK + j];
    const float pzj = xb[2*S_TOK + j], ej  = xb[3*S_TOK + j];

    const float pti = sqrtf(pxi*pxi + pyi*pyi);
    const float ptj = sqrtf(pxj*pxj + pyj*pyj);
    const float rapi = 0.5f * log1pf(2.0f * pzi / fmaxf(ei - pzi, 1e-20f));
    const float rapj = 0.5f * log1pf(2.0f * pzj / fmaxf(ej - pzj, 1e-20f));
    const float phii = atan2f(pyi, pxi);
    const float phij = atan2f(pyj, pxj);

    const float PI_F    = 3.14159265358979323846f;
    const float TWOPI_F = 6.28318530717958647692f;
    float dx   = phii - phij + PI_F;
    float dphi = dx - TWOPI_F * floorf(dx * (1.0f / TWOPI_F)) - PI_F;
    float drap = rapi - rapj;
    float delta = sqrtf(drap*drap + dphi*dphi);
    float lndelta = logf(fmaxf(delta, 1e-8f));
    float ptmin = fminf(pti, ptj);
    float f0 = logf(fmaxf(ptmin * delta, 1e-8f));
    float f1 = logf(fmaxf(ptmin / fmaxf(pti + ptj, 1e-8f), 1e-8f));
    float f2 = lndelta;
    float sx = pxi + pxj, sy = pyi + pyj, sz = pzi + pzj, se = ei + ej;
    float f3 = logf(fmaxf(se*se - sx*sx - sy*sy - sz*sz, 1e-8f));

    // ---- layer 1 (fp32) + gelu -> bf16 -> LDS (swizzled rows) ----
    const float* A1 = ws + OFF_A1;
    const float* C1 = ws + OFF_C1;
    #pragma unroll
    for (int oc = 0; oc < 8; ++oc) {
        unsigned pk[4];
        #pragma unroll
        for (int q = 0; q < 4; ++q) {
            const int o0 = oc*8 + 2*q;
            float z0 = C1[o0]   + A1[o0*4+0]*f0 + A1[o0*4+1]*f1
                                + A1[o0*4+2]*f2 + A1[o0*4+3]*f3;
            float z1 = C1[o0+1] + A1[(o0+1)*4+0]*f0 + A1[(o0+1)*4+1]*f1
                                + A1[(o0+1)*4+2]*f2 + A1[(o0+1)*4+3]*f3;
            z0 = gelu_fast(z0);
            z1 = gelu_fast(z1);
            pk[q] = (unsigned)f2bf(z0) | ((unsigned)f2bf(z1) << 16);
        }
        uint4 v; v.x = pk[0]; v.y = pk[1]; v.z = pk[2]; v.w = pk[3];
        *reinterpret_cast<uint4*>(Abuf + SWZ(tid, oc*16)) = v;
    }
    __syncthreads();

    const unsigned short* A2bf = (const unsigned short*)(ws + OFF_BF);
    const unsigned short* A3bf = A2bf + 4096;
    const float* C2 = ws + OFF_C2;
    const float* C3 = ws + OFF_C3;

    // ---- layer 2 ----
    f32x4 acc2[4][4];
    #pragma unroll
    for (int mt = 0; mt < 4; ++mt)
        #pragma unroll
        for (int nt = 0; nt < 4; ++nt)
            acc2[mt][nt] = f32x4{0.f, 0.f, 0.f, 0.f};
    #pragma unroll
    for (int kt = 0; kt < 2; ++kt) {
        bf16x8 af[4];
        #pragma unroll
        for (int mt = 0; mt < 4; ++mt)
            af[mt] = *reinterpret_cast<const bf16x8*>(
                Abuf + SWZ(wv*64 + mt*16 + lcol, kt*64 + lgrp*16));
        #pragma unroll
        for (int nt = 0; nt < 4; ++nt) {
            bf16x8 wf = *reinterpret_cast<const bf16x8*>(
                A2bf + (nt*16 + lcol)*64 + kt*32 + lgrp*8);
            #pragma unroll
            for (int mt = 0; mt < 4; ++mt)
                acc2[mt][nt] = __builtin_amdgcn_mfma_f32_16x16x32_bf16(
                    af[mt], wf, acc2[mt][nt], 0, 0, 0);
        }
    }
    __syncthreads();   // all layer-2 reads of Abuf done

    // bias + gelu -> bf16 a2 back into Abuf (D layout: row=4*lgrp+r, col=lcol)
    #pragma unroll
    for (int nt = 0; nt < 4; ++nt) {
        const float bias = C2[nt*16 + lcol];
        #pragma unroll
        for (int mt = 0; mt < 4; ++mt)
            #pragma unroll
            for (int r = 0; r < 4; ++r) {
                float z = acc2[mt][nt][r] + bias;
                *reinterpret_cast<unsigned short*>(
                    Abuf + SWZ(wv*64 + mt*16 + 4*lgrp + r, (nt*16 + lcol)*2))
                    = f2bf(gelu_fast(z));
            }
    }
    __syncthreads();

    const size_t ybase = (size_t)b * 64 * (S_TOK * S_TOK);
    const bool diag = (I == J);

    // ---- layer 3 pass 1 (direct region) ----
    {
        f32x4 acc3[4][4];
        #pragma unroll
        for (int mt = 0; mt < 4; ++mt)
            #pragma unroll
            for (int nt = 0; nt < 4; ++nt)
                acc3[mt][nt] = f32x4{0.f, 0.f, 0.f, 0.f};
        #pragma unroll
        for (int kt = 0; kt < 2; ++kt) {
            bf16x8 af[4];
            #pragma unroll
            for (int mt = 0; mt < 4; ++mt)
                af[mt] = *reinterpret_cast<const bf16x8*>(
                    Abuf + SWZ(wv*64 + mt*16 + lcol, kt*64 + lgrp*16));
            #pragma unroll
            for (int nt = 0; nt < 4; ++nt) {
                bf16x8 wf = *reinterpret_cast<const bf16x8*>(
                    A3bf + (nt*16 + lcol)*64 + kt*32 + lgrp*8);
                #pragma unroll
                for (int mt = 0; mt < 4; ++mt)
                    acc3[mt][nt] = __builtin_amdgcn_mfma_f32_16x16x32_bf16(
                        af[mt], wf, acc3[mt][nt], 0, 0, 0);
            }
        }
        // direct stores: pair row = wv*64+mt*16+4*lgrp+r -> (il=4wv+mt,
        // jl=4lgrp+r consecutive => dwordx4); channel o = nt*16+lcol.
        #pragma unroll
        for (int nt = 0; nt < 4; ++nt) {
            const float bias3 = C3[nt*16 + lcol];
            #pragma unroll
            for (int mt = 0; mt < 4; ++mt) {
                f32x4 v = acc3[mt][nt] + bias3;
                *reinterpret_cast<f32x4*>(
                    &y[ybase + (size_t)(nt*16 + lcol)*(S_TOK*S_TOK)
                             + (16*I + 4*wv + mt)*S_TOK + 16*J + 4*lgrp]) = v;
            }
        }
    }

    // ---- layer 3 pass 2 (mirror region, transposed-pair A-frags) ----
    if (!diag) {
        f32x4 accT[4][4];
        #pragma unroll
        for (int mt = 0; mt < 4; ++mt)
            #pragma unroll
            for (int nt = 0; nt < 4; ++nt)
                accT[mt][nt] = f32x4{0.f, 0.f, 0.f, 0.f};
        #pragma unroll
        for (int kt = 0; kt < 2; ++kt) {
            bf16x8 afT[4];
            #pragma unroll
            for (int mt = 0; mt < 4; ++mt)
                afT[mt] = *reinterpret_cast<const bf16x8*>(
                    Abuf + SWZ(lcol*16 + wv*4 + mt, kt*64 + lgrp*16));
            #pragma unroll
            for (int nt = 0; nt < 4; ++nt) {
                bf16x8 wf = *reinterpret_cast<const bf16x8*>(
                    A3bf + (nt*16 + lcol)*64 + kt*32 + lgrp*8);
                #pragma unroll
                for (int mt = 0; mt < 4; ++mt)
                    accT[mt][nt] = __builtin_amdgcn_mfma_f32_16x16x32_bf16(
                        afT[mt], wf, accT[mt][nt], 0, 0, 0);
            }
        }
        // mirror stores: output pair-row p' = wv*64+mt*16+4*lgrp+r holds
        // a2[swap(p')] product = h(i=16I+(4lgrp+r), j=16J+(4wv+mt)) ->
        // y[o][16J + 4wv+mt][16I + 4lgrp + r]  (r consecutive => dwordx4).
        #pragma unroll
        for (int nt = 0; nt < 4; ++nt) {
            const float bias3 = C3[nt*16 + lcol];
            #pragma unroll
            for (int mt = 0; mt < 4; ++mt) {
                f32x4 v = accT[mt][nt] + bias3;
                *reinterpret_cast<f32x4*>(
                    &y[ybase + (size_t)(nt*16 + lcol)*(S_TOK*S_TOK)
                             + (16*J + 4*wv + mt)*S_TOK + 16*I + 4*lgrp]) = v;
            }
        }
    }
}

extern "C" void kernel_launch(void* const* d_in, const int* in_sizes, int n_in,
                              void* d_out, int out_size, void* d_ws, size_t ws_size,
                              hipStream_t stream) {
    const float* x    = (const float*)d_in[0];
    const float* bn0g = (const float*)d_in[1];
    const float* bn0b = (const float*)d_in[2];
    const float* bn0m = (const float*)d_in[3];
    const float* bn0v = (const float*)d_in[4];
    const float* W1   = (const float*)d_in[5];
    const float* b1   = (const float*)d_in[6];
    const float* bn1g = (const float*)d_in[7];
    const float* bn1b = (const float*)d_in[8];
    const float* bn1m = (const float*)d_in[9];
    const float* bn1v = (const float*)d_in[10];
    const float* W2   = (const float*)d_in[11];
    const float* b2   = (const float*)d_in[12];
    const float* bn2g = (const float*)d_in[13];
    const float* bn2b = (const float*)d_in[14];
    const float* bn2m = (const float*)d_in[15];
    const float* bn2v = (const float*)d_in[16];
    const float* W3   = (const float*)d_in[17];
    const float* b3   = (const float*)d_in[18];
    const float* bn3g = (const float*)d_in[19];
    const float* bn3b = (const float*)d_in[20];
    const float* bn3m = (const float*)d_in[21];
    const float* bn3v = (const float*)d_in[22];

    float* ws = (float*)d_ws;
    float* y  = (float*)d_out;

    fold_weights_kernel<<<1, 64, 0, stream>>>(
        bn0g, bn0b, bn0m, bn0v, W1, b1, bn1g, bn1b, bn1m, bn1v,
        W2, b2, bn2g, bn2b, bn2m, bn2v, W3, b3, bn3g, bn3b, bn3m, bn3v, ws);

    dim3 grid(36, 64);
    pair_mlp_mfma<<<grid, 256, 0, stream>>>(x, ws, y);
}

// Round 15
// 75.395 us; speedup vs baseline: 3.1438x; 1.1075x over previous
//
#include <hip/hip_runtime.h>
#include <math.h>

#define S_TOK 128
#define PS_O 257    // float stride for mirror staging rows

// Abuf: 256 rows x 128 bytes (64 bf16) with XOR swizzle -> 32 KiB exact.
// Swizzle keeps b128 row writes (layer1) and b128 frag reads (layer2/3)
// bank-conflict-free; bijective within each row.
#define SWZ(row, byteoff) ((((row) * 128) + (byteoff)) ^ (((row) & 7) << 4))

// ws float layout
#define OFF_A1 0      // [64][4] f32 folded layer-1 weights
#define OFF_C1 256    // [64] f32
#define OFF_C2 320
#define OFF_C3 384
#define OFF_BF 448    // ushort region: A2bf[64*64], then A3bf[64*64]

using bf16x8 = __attribute__((ext_vector_type(8))) __bf16;
using f32x4  = __attribute__((ext_vector_type(4))) float;

__device__ __forceinline__ unsigned short f2bf(float v) {
    unsigned u = __builtin_bit_cast(unsigned, v);
    u += 0x7fffu + ((u >> 16) & 1u);      // round-to-nearest-even
    return (unsigned short)(u >> 16);
}

// tanh-form gelu via HW transcendentals (~9 VALU ops vs ~105 for libm erff).
__device__ __forceinline__ float gelu_fast(float v) {
    float v2 = v * v;
    float z  = v * fmaf(0.044715f, v2, 1.0f);
    float u  = z * 2.3022082f;            // 2 * 0.7978845608 * log2(e)
    float e;
    asm("v_exp_f32 %0, %1" : "=v"(e) : "v"(u));
    float d = e + 1.0f;
    float r;
    asm("v_rcp_f32 %0, %1" : "=v"(r) : "v"(d));
    return fmaf(-v, r, v);                // v*(1-r); e=inf -> v, e=0 -> 0
}

// Workgroup barrier that waits only for LDS ops (lgkmcnt), NOT vmcnt.
// __syncthreads() would emit s_waitcnt vmcnt(0) and drain the global-store
// queue at every barrier of the store phase; our stores have no readers
// until kernel end, so letting them stay in flight is safe (T3/T4 pattern).
__device__ __forceinline__ void lds_barrier() {
    asm volatile("s_waitcnt lgkmcnt(0)" ::: "memory");
    __builtin_amdgcn_s_barrier();
}

__global__ void fold_weights_kernel(
    const float* __restrict__ bn0g, const float* __restrict__ bn0b,
    const float* __restrict__ bn0m, const float* __restrict__ bn0v,
    const float* __restrict__ W1,  const float* __restrict__ b1,
    const float* __restrict__ bn1g, const float* __restrict__ bn1b,
    const float* __restrict__ bn1m, const float* __restrict__ bn1v,
    const float* __restrict__ W2,  const float* __restrict__ b2,
    const float* __restrict__ bn2g, const float* __restrict__ bn2b,
    const float* __restrict__ bn2m, const float* __restrict__ bn2v,
    const float* __restrict__ W3,  const float* __restrict__ b3,
    const float* __restrict__ bn3g, const float* __restrict__ bn3b,
    const float* __restrict__ bn3m, const float* __restrict__ bn3v,
    float* __restrict__ ws)
{
    int o = threadIdx.x;
    if (o >= 64) return;
    float s0[4], t0[4];
    #pragma unroll
    for (int c = 0; c < 4; ++c) {
        float s = bn0g[c] / sqrtf(bn0v[c] + 1e-5f);
        s0[c] = s;
        t0[c] = bn0b[c] - bn0m[c] * s;
    }
    float s1 = bn1g[o] / sqrtf(bn1v[o] + 1e-5f);
    float acc = b1[o] - bn1m[o];
    #pragma unroll
    for (int c = 0; c < 4; ++c) {
        float w = W1[o*4 + c];
        ws[OFF_A1 + o*4 + c] = s1 * w * s0[c];
        acc += w * t0[c];
    }
    ws[OFF_C1 + o] = s1 * acc + bn1b[o];

    unsigned short* wsbf = (unsigned short*)(ws + OFF_BF);
    unsigned short* A2bf = wsbf;
    unsigned short* A3bf = wsbf + 4096;

    float s2 = bn2g[o] / sqrtf(bn2v[o] + 1e-5f);
    for (int c = 0; c < 64; ++c) A2bf[o*64 + c] = f2bf(W2[o*64 + c] * s2);
    ws[OFF_C2 + o] = (b2[o] - bn2m[o]) * s2 + bn2b[o];

    float s3 = bn3g[o] / sqrtf(bn3v[o] + 1e-5f);
    for (int c = 0; c < 64; ++c) A3bf[o*64 + c] = f2bf(W3[o*64 + c] * s3);
    ws[OFF_C3 + o] = (b3[o] - bn3m[o]) * s3 + bn3b[o];
}

// Block = (tril tile t, batch b). 256 threads = 4 waves.
// h(i,j)=h(j,i): diagonal tiles write directly (no LDS); off-diagonal tiles
// write the (I,J) region straight from registers and the (J,I) mirror via a
// rotated LDS staging tile.
// launch_bounds (256,4): (256,5) forced <=~100 VGPR and spilled: 116us vs 76us.
// Session evidence (r3-r14): three store-path variants all 76us; issue-side
// reductions null; occupancy/pipelining blocked by VGPR pressure. This is the
// phase-aligned serial floor: VALU ~17 + LDS ~20 + stores ~38 us.
__global__ __launch_bounds__(256, 4) void pair_mlp_mfma(
    const float* __restrict__ x, const float* __restrict__ ws,
    float* __restrict__ y)
{
    __shared__ __align__(16) unsigned char Abuf[32768];

    const int t = blockIdx.x;
    const int b = blockIdx.y;
    int I = (int)((sqrtf(8.0f * (float)t + 1.0f) - 1.0f) * 0.5f);
    while ((I + 1) * (I + 2) / 2 <= t) ++I;
    while (I * (I + 1) / 2 > t) --I;
    const int J = t - I * (I + 1) / 2;

    const int tid  = threadIdx.x;
    const int lane = tid & 63;
    const int wv   = tid >> 6;      // wave 0..3
    const int lcol = lane & 15;     // MFMA row/col-in-frag
    const int lgrp = lane >> 4;     // MFMA k-group 0..3

    // ---- pairwise LV features (fp32, jnp semantics) ----
    const int li = tid >> 4;
    const int lj = tid & 15;
    const int i = I * 16 + li;
    const int j = J * 16 + lj;

    const float* xb = x + (size_t)b * 4 * S_TOK;
    const float pxi = xb[0*S_TOK + i], pyi = xb[1*S_TOK + i];
    const float pzi = xb[2*S_TOK + i], ei  = xb[3*S_TOK + i];
    const float pxj = xb[0*S_TOK + j], pyj = xb[1*S_TOK + j];
    const float pzj = xb[2*S_TOK + j], ej  = xb[3*S_TOK + j];

    const float pti = sqrtf(pxi*pxi + pyi*pyi);
    const float ptj = sqrtf(pxj*pxj + pyj*pyj);
    const float rapi = 0.5f * log1pf(2.0f * pzi / fmaxf(ei - pzi, 1e-20f));
    const float rapj = 0.5f * log1pf(2.0f * pzj / fmaxf(ej - pzj, 1e-20f));
    const float phii = atan2f(pyi, pxi);
    const float phij = atan2f(pyj, pxj);

    const float PI_F    = 3.14159265358979323846f;
    const float TWOPI_F = 6.28318530717958647692f;
    float dx   = phii - phij + PI_F;
    float dphi = dx - TWOPI_F * floorf(dx * (1.0f / TWOPI_F)) - PI_F;
    float drap = rapi - rapj;
    float delta = sqrtf(drap*drap + dphi*dphi);
    float lndelta = logf(fmaxf(delta, 1e-8f));
    float ptmin = fminf(pti, ptj);
    float f0 = logf(fmaxf(ptmin * delta, 1e-8f));
    float f1 = logf(fmaxf(ptmin / fmaxf(pti + ptj, 1e-8f), 1e-8f));
    float f2 = lndelta;
    float sx = pxi + pxj, sy = pyi + pyj, sz = pzi + pzj, se = ei + ej;
    float f3 = logf(fmaxf(se*se - sx*sx - sy*sy - sz*sz, 1e-8f));

    // ---- layer 1 (fp32) + gelu -> bf16 -> LDS (swizzled rows) ----
    const float* A1 = ws + OFF_A1;
    const float* C1 = ws + OFF_C1;
    #pragma unroll
    for (int oc = 0; oc < 8; ++oc) {
        unsigned pk[4];
        #pragma unroll
        for (int q = 0; q < 4; ++q) {
            const int o0 = oc*8 + 2*q;
            float z0 = C1[o0]   + A1[o0*4+0]*f0 + A1[o0*4+1]*f1
                                + A1[o0*4+2]*f2 + A1[o0*4+3]*f3;
            float z1 = C1[o0+1] + A1[(o0+1)*4+0]*f0 + A1[(o0+1)*4+1]*f1
                                + A1[(o0+1)*4+2]*f2 + A1[(o0+1)*4+3]*f3;
            z0 = gelu_fast(z0);
            z1 = gelu_fast(z1);
            pk[q] = (unsigned)f2bf(z0) | ((unsigned)f2bf(z1) << 16);
        }
        uint4 v; v.x = pk[0]; v.y = pk[1]; v.z = pk[2]; v.w = pk[3];
        *reinterpret_cast<uint4*>(Abuf + SWZ(tid, oc*16)) = v;
    }
    __syncthreads();

    const unsigned short* A2bf = (const unsigned short*)(ws + OFF_BF);
    const unsigned short* A3bf = A2bf + 4096;
    const float* C2 = ws + OFF_C2;
    const float* C3 = ws + OFF_C3;

    // ---- layer 2 ----
    f32x4 acc2[4][4];
    #pragma unroll
    for (int mt = 0; mt < 4; ++mt)
        #pragma unroll
        for (int nt = 0; nt < 4; ++nt)
            acc2[mt][nt] = f32x4{0.f, 0.f, 0.f, 0.f};
    {
        bf16x8 wf[4][2];
        #pragma unroll
        for (int nt = 0; nt < 4; ++nt)
            #pragma unroll
            for (int kt = 0; kt < 2; ++kt)
                wf[nt][kt] = *reinterpret_cast<const bf16x8*>(
                    A2bf + (nt*16 + lcol)*64 + kt*32 + lgrp*8);
        #pragma unroll
        for (int kt = 0; kt < 2; ++kt) {
            bf16x8 af[4];
            #pragma unroll
            for (int mt = 0; mt < 4; ++mt)
                af[mt] = *reinterpret_cast<const bf16x8*>(
                    Abuf + SWZ(wv*64 + mt*16 + lcol, kt*64 + lgrp*16));
            #pragma unroll
            for (int mt = 0; mt < 4; ++mt)
                #pragma unroll
                for (int nt = 0; nt < 4; ++nt)
                    acc2[mt][nt] = __builtin_amdgcn_mfma_f32_16x16x32_bf16(
                        af[mt], wf[nt][kt], acc2[mt][nt], 0, 0, 0);
        }
    }
    __syncthreads();   // all layer-2 reads of Abuf done

    // bias + gelu -> bf16 a2 back into Abuf (D layout: row=4*lgrp+r, col=lcol)
    #pragma unroll
    for (int nt = 0; nt < 4; ++nt) {
        const float bias = C2[nt*16 + lcol];
        #pragma unroll
        for (int mt = 0; mt < 4; ++mt)
            #pragma unroll
            for (int r = 0; r < 4; ++r) {
                float z = acc2[mt][nt][r] + bias;
                *reinterpret_cast<unsigned short*>(
                    Abuf + SWZ(wv*64 + mt*16 + 4*lgrp + r, (nt*16 + lcol)*2))
                    = f2bf(gelu_fast(z));
            }
    }
    __syncthreads();

    // ---- layer 3 (no gelu) ----
    f32x4 acc3[4][4];
    #pragma unroll
    for (int mt = 0; mt < 4; ++mt)
        #pragma unroll
        for (int nt = 0; nt < 4; ++nt)
            acc3[mt][nt] = f32x4{0.f, 0.f, 0.f, 0.f};
    {
        bf16x8 wf[4][2];
        #pragma unroll
        for (int nt = 0; nt < 4; ++nt)
            #pragma unroll
            for (int kt = 0; kt < 2; ++kt)
                wf[nt][kt] = *reinterpret_cast<const bf16x8*>(
                    A3bf + (nt*16 + lcol)*64 + kt*32 + lgrp*8);
        #pragma unroll
        for (int kt = 0; kt < 2; ++kt) {
            bf16x8 af[4];
            #pragma unroll
            for (int mt = 0; mt < 4; ++mt)
                af[mt] = *reinterpret_cast<const bf16x8*>(
                    Abuf + SWZ(wv*64 + mt*16 + lcol, kt*64 + lgrp*16));
            #pragma unroll
            for (int mt = 0; mt < 4; ++mt)
                #pragma unroll
                for (int nt = 0; nt < 4; ++nt)
                    acc3[mt][nt] = __builtin_amdgcn_mfma_f32_16x16x32_bf16(
                        af[mt], wf[nt][kt], acc3[mt][nt], 0, 0, 0);
        }
    }

    // ---- output ----
    // acc3[mt][nt][r]: pair row = wv*64+mt*16+4*lgrp+r -> il=4*wv+mt,
    // jl=4*lgrp+r (consecutive over r => dwordx4); channel o = nt*16+lcol.
    const size_t ybase = (size_t)b * 64 * (S_TOK * S_TOK);
    const bool diag = (I == J);

    if (diag) {
        // direct-only, straight from registers, no LDS, no barriers
        #pragma unroll
        for (int nt = 0; nt < 4; ++nt) {
            const float bias3 = C3[nt*16 + lcol];
            #pragma unroll
            for (int mt = 0; mt < 4; ++mt) {
                f32x4 v = acc3[mt][nt] + bias3;
                *reinterpret_cast<f32x4*>(
                    &y[ybase + (size_t)(nt*16 + lcol)*(S_TOK*S_TOK)
                             + (16*I + 4*wv + mt)*S_TOK + 16*J + 4*lgrp]) = v;
            }
        }
    } else {
        float* Obuf = reinterpret_cast<float*>(Abuf);   // [16][PS_O] mirror staging
        const int jd = tid & 15;
        const int g2 = (tid >> 4) & 3;
        lds_barrier();   // all layer-3 Abuf reads done before Obuf clobbers

        for (int nt = 0; nt < 4; ++nt) {
            const float bias3 = C3[nt*16 + lcol];
            #pragma unroll
            for (int mt = 0; mt < 4; ++mt) {
                f32x4 v = acc3[mt][nt] + bias3;
                // direct store from registers
                *reinterpret_cast<f32x4*>(
                    &y[ybase + (size_t)(nt*16 + lcol)*(S_TOK*S_TOK)
                             + (16*I + 4*wv + mt)*S_TOK + 16*J + 4*lgrp]) = v;
                // mirror staging: [o_local][il*16 + ((jl+il)&15)]
                const int il = 4*wv + mt;
                #pragma unroll
                for (int r = 0; r < 4; ++r) {
                    const int jl = 4*lgrp + r;
                    Obuf[lcol*PS_O + il*16 + ((jl + il) & 15)] = v[r];
                }
            }
            lds_barrier();   // staging visible; stores stay in flight
            #pragma unroll
            for (int k = 0; k < 16; ++k) {
                const int ol = 4*(k & 3) + wv;
                const int o  = nt*16 + ol;
                const int il = 4*(k >> 2) + g2;
                // y[o][16J+il][16I+jd] = h(i=16I+jd, j=16J+il) stored at (jd,il)
                const float vmir = Obuf[ol*PS_O + jd*16 + ((il + jd) & 15)];
                y[ybase + (size_t)o*(S_TOK*S_TOK) + (16*J + il)*S_TOK + 16*I + jd] = vmir;
            }
            lds_barrier();   // Obuf reads done before next-nt staging
        }
    }
}

extern "C" void kernel_launch(void* const* d_in, const int* in_sizes, int n_in,
                              void* d_out, int out_size, void* d_ws, size_t ws_size,
                              hipStream_t stream) {
    const float* x    = (const float*)d_in[0];
    const float* bn0g = (const float*)d_in[1];
    const float* bn0b = (const float*)d_in[2];
    const float* bn0m = (const float*)d_in[3];
    const float* bn0v = (const float*)d_in[4];
    const float* W1   = (const float*)d_in[5];
    const float* b1   = (const float*)d_in[6];
    const float* bn1g = (const float*)d_in[7];
    const float* bn1b = (const float*)d_in[8];
    const float* bn1m = (const float*)d_in[9];
    const float* bn1v = (const float*)d_in[10];
    const float* W2   = (const float*)d_in[11];
    const float* b2   = (const float*)d_in[12];
    const float* bn2g = (const float*)d_in[13];
    const float* bn2b = (const float*)d_in[14];
    const float* bn2m = (const float*)d_in[15];
    const float* bn2v = (const float*)d_in[16];
    const float* W3   = (const float*)d_in[17];
    const float* b3   = (const float*)d_in[18];
    const float* bn3g = (const float*)d_in[19];
    const float* bn3b = (const float*)d_in[20];
    const float* bn3m = (const float*)d_in[21];
    const float* bn3v = (const float*)d_in[22];

    float* ws = (float*)d_ws;
    float* y  = (float*)d_out;

    fold_weights_kernel<<<1, 64, 0, stream>>>(
        bn0g, bn0b, bn0m, bn0v, W1, b1, bn1g, bn1b, bn1m, bn1v,
        W2, b2, bn2g, bn2b, bn2m, bn2v, W3, b3, bn3g, bn3b, bn3m, bn3v, ws);

    dim3 grid(36, 64);
    pair_mlp_mfma<<<grid, 256, 0, stream>>>(x, ws, y);
}